// Round 9
// baseline (742.626 us; speedup 1.0000x reference)
//
#include <hip/hip_runtime.h>
#include <hip/hip_cooperative_groups.h>
#include <cstdint>
#include <cstddef>

namespace cg = cooperative_groups;

#define NPTS 2048
#define NBAT 8

typedef unsigned long long ull;
typedef __attribute__((ext_vector_type(8))) short bf16x8;
typedef __attribute__((ext_vector_type(4))) float f32x4;

__device__ __forceinline__ float4 ld4(const float* p){ return *reinterpret_cast<const float4*>(p); }
__device__ __forceinline__ void st4(float* p, float4 v){ *reinterpret_cast<float4*>(p) = v; }
__device__ __forceinline__ unsigned short f2bf(float f){
    unsigned int u = __float_as_uint(f);
    u += 0x7FFFu + ((u >> 16) & 1u);
    return (unsigned short)(u >> 16);
}
__device__ __forceinline__ float bf2f(unsigned short h){
    return __uint_as_float(((unsigned int)h) << 16);
}

__device__ __forceinline__ float blk_red_sum(float v, float* red){
    #pragma unroll
    for (int o = 32; o > 0; o >>= 1) v += __shfl_xor(v, o, 64);
    int wid = threadIdx.x >> 6;
    if ((threadIdx.x & 63) == 0) red[wid] = v;
    __syncthreads();
    v = red[0] + red[1] + red[2] + red[3];
    __syncthreads();
    return v;
}

// ---------------------------------------------------------------------------
// MFMA linear (R5 version): out[b,d,n] = sum_c W[d,c]*X[b,c,n] (+bias)
// MODE: 0=fp32 out, 1=bf16 out, 2=qT hi/lo out.
// ---------------------------------------------------------------------------
template<int CIN, int COUT, int TD, int TN, int MODE, bool BIAS>
__global__ __launch_bounds__(256) void lin_mfma_kernel(
        const float* __restrict__ W, const float* __restrict__ X,
        const float* __restrict__ bias, void* __restrict__ outv,
        void* __restrict__ outv2)
{
    constexpr int WD  = TD / 16;
    constexpr int NPW = TN * WD / 4;
    constexpr int FB  = NPW / 16;
    constexpr int KS  = CIN / 32;
    __shared__ unsigned short Xhi[TN * CIN];
    __shared__ unsigned short Xlo[TN * CIN];
    const int tid = threadIdx.x;
    const int lane = tid & 63;
    const int w = tid >> 6;
    const int g = lane >> 4;
    const int l15 = lane & 15;
    const int b = blockIdx.z;
    const int d0 = blockIdx.y * TD;
    const int n0 = blockIdx.x * TN;
    const int dw = (w % WD) * 16;
    const int nw = (w / WD) * NPW;

    bf16x8 Whi[KS], Wlo[KS];
    {
        const int d = d0 + dw + l15;
        #pragma unroll
        for (int ks = 0; ks < KS; ++ks) {
            float4 a = ld4(&W[(size_t)d * CIN + ks * 32 + g * 8]);
            float4 bq = ld4(&W[(size_t)d * CIN + ks * 32 + g * 8 + 4]);
            float vv[8] = {a.x, a.y, a.z, a.w, bq.x, bq.y, bq.z, bq.w};
            bf16x8 h8, l8;
            #pragma unroll
            for (int e = 0; e < 8; ++e) {
                unsigned short hh = f2bf(vv[e]);
                h8[e] = (short)hh;
                l8[e] = (short)f2bf(vv[e] - bf2f(hh));
            }
            Whi[ks] = h8; Wlo[ks] = l8;
        }
    }
    constexpr int TN4 = TN / 4;
    constexpr int NF = (TN * CIN) / 1024;
    #pragma unroll
    for (int f = 0; f < NF; ++f) {
        int idx = tid + 256 * f;
        int c = idx / TN4;
        int n = (idx % TN4) * 4;
        float4 xv = ld4(&X[((size_t)(b * CIN + c)) * NPTS + n0 + n]);
        float vv[4] = {xv.x, xv.y, xv.z, xv.w};
        #pragma unroll
        for (int j2 = 0; j2 < 4; ++j2) {
            int nn = n + j2;
            int cp = (c + nn * 8) & (CIN - 1);
            unsigned short hh = f2bf(vv[j2]);
            Xhi[nn * CIN + cp] = hh;
            Xlo[nn * CIN + cp] = f2bf(vv[j2] - bf2f(hh));
        }
    }
    __syncthreads();

    f32x4 acc[FB];
    #pragma unroll
    for (int fb = 0; fb < FB; ++fb) acc[fb] = (f32x4){0.f, 0.f, 0.f, 0.f};
    #pragma unroll
    for (int ks = 0; ks < KS; ++ks) {
        #pragma unroll
        for (int fb = 0; fb < FB; ++fb) {
            int n = nw + fb * 16 + l15;
            int cp = (ks * 32 + g * 8 + n * 8) & (CIN - 1);
            bf16x8 xh = *reinterpret_cast<bf16x8*>(&Xhi[n * CIN + cp]);
            bf16x8 xl = *reinterpret_cast<bf16x8*>(&Xlo[n * CIN + cp]);
            acc[fb] = __builtin_amdgcn_mfma_f32_16x16x32_bf16(Wlo[ks], xh, acc[fb], 0, 0, 0);
            acc[fb] = __builtin_amdgcn_mfma_f32_16x16x32_bf16(Whi[ks], xl, acc[fb], 0, 0, 0);
            acc[fb] = __builtin_amdgcn_mfma_f32_16x16x32_bf16(Whi[ks], xh, acc[fb], 0, 0, 0);
        }
    }
    const int dbase = d0 + dw + g * 4;
    float bb[4] = {0.f, 0.f, 0.f, 0.f};
    if (BIAS) {
        float4 b4 = ld4(&bias[dbase]);
        bb[0] = b4.x; bb[1] = b4.y; bb[2] = b4.z; bb[3] = b4.w;
    }
    #pragma unroll
    for (int fb = 0; fb < FB; ++fb) {
        int ncol = n0 + nw + fb * 16 + l15;
        if (MODE == 2) {
            unsigned short* qh = (unsigned short*)outv;
            unsigned short* ql = (unsigned short*)outv2;
            ushort4 hh, ll;
            float q0 = acc[fb][0], q1 = acc[fb][1], q2 = acc[fb][2], q3 = acc[fb][3];
            hh.x = f2bf(q0); ll.x = f2bf(q0 - bf2f(hh.x));
            hh.y = f2bf(q1); ll.y = f2bf(q1 - bf2f(hh.y));
            hh.z = f2bf(q2); ll.z = f2bf(q2 - bf2f(hh.z));
            hh.w = f2bf(q3); ll.w = f2bf(q3 - bf2f(hh.w));
            *reinterpret_cast<ushort4*>(&qh[((size_t)b * NPTS + ncol) * 32 + dbase]) = hh;
            *reinterpret_cast<ushort4*>(&ql[((size_t)b * NPTS + ncol) * 32 + dbase]) = ll;
        } else if (MODE == 1) {
            unsigned short* ob = (unsigned short*)outv;
            #pragma unroll
            for (int r = 0; r < 4; ++r)
                ob[((size_t)(b * COUT + dbase + r)) * NPTS + ncol] = f2bf(acc[fb][r] + bb[r]);
        } else {
            float* ob = (float*)outv;
            #pragma unroll
            for (int r = 0; r < 4; ++r)
                ob[((size_t)(b * COUT + dbase + r)) * NPTS + ncol] = acc[fb][r] + bb[r];
        }
    }
}

// row softmax stats via on-the-fly e = qT q (fallback). grid (NPTS/16, NBAT).
__global__ __launch_bounds__(256) void rowstats_fused_kernel(
        const unsigned short* __restrict__ qThi, const unsigned short* __restrict__ qTlo,
        float* __restrict__ rowm, float* __restrict__ rowinv)
{
    __shared__ float pm[4][16];
    __shared__ float ps[4][16];
    const int lane = threadIdx.x & 63;
    const int w = threadIdx.x >> 6;
    const int b = blockIdx.y;
    const int i0 = blockIdx.x * 16;
    const int g = lane >> 4;
    const int l15 = lane & 15;
    const int iR = i0 + l15;
    const bf16x8 bhi = *reinterpret_cast<const bf16x8*>(&qThi[((size_t)b * NPTS + iR) * 32 + g * 8]);
    const bf16x8 blo = *reinterpret_cast<const bf16x8*>(&qTlo[((size_t)b * NPTS + iR) * 32 + g * 8]);
    float m = -1e30f, s = 0.f;
    for (int t = w * 32; t < w * 32 + 32; ++t) {
        int jr = t * 16 + l15;
        const bf16x8 ahi = *reinterpret_cast<const bf16x8*>(&qThi[((size_t)b * NPTS + jr) * 32 + g * 8]);
        const bf16x8 alo = *reinterpret_cast<const bf16x8*>(&qTlo[((size_t)b * NPTS + jr) * 32 + g * 8]);
        f32x4 e4 = {0.f, 0.f, 0.f, 0.f};
        e4 = __builtin_amdgcn_mfma_f32_16x16x32_bf16(alo, bhi, e4, 0, 0, 0);
        e4 = __builtin_amdgcn_mfma_f32_16x16x32_bf16(ahi, blo, e4, 0, 0, 0);
        e4 = __builtin_amdgcn_mfma_f32_16x16x32_bf16(ahi, bhi, e4, 0, 0, 0);
        float tm = fmaxf(fmaxf(e4[0], e4[1]), fmaxf(e4[2], e4[3]));
        float nm = fmaxf(m, tm);
        s *= __expf(m - nm);
        m = nm;
        s += __expf(e4[0] - m) + __expf(e4[1] - m) + __expf(e4[2] - m) + __expf(e4[3] - m);
    }
    #pragma unroll
    for (int o = 16; o <= 32; o <<= 1) {
        float om = __shfl_xor(m, o, 64);
        float os = __shfl_xor(s, o, 64);
        float nm = fmaxf(m, om);
        s = s * __expf(m - nm) + os * __expf(om - nm);
        m = nm;
    }
    if (lane < 16) { pm[w][l15] = m; ps[w][l15] = s; }
    __syncthreads();
    if (threadIdx.x < 16) {
        float m0 = pm[0][threadIdx.x], m1 = pm[1][threadIdx.x];
        float m2 = pm[2][threadIdx.x], m3 = pm[3][threadIdx.x];
        float mf = fmaxf(fmaxf(m0, m1), fmaxf(m2, m3));
        float sf = ps[0][threadIdx.x] * __expf(m0 - mf)
                 + ps[1][threadIdx.x] * __expf(m1 - mf)
                 + ps[2][threadIdx.x] * __expf(m2 - mf)
                 + ps[3][threadIdx.x] * __expf(m3 - mf);
        rowm[(size_t)b * NPTS + i0 + threadIdx.x] = mf;
        rowinv[(size_t)b * NPTS + i0 + threadIdx.x] = 1.f / sf;
    }
}

// Fused attention (R5 version, fallback): dbuf LDS, 1 barrier/step, reg prefetch.
__global__ __launch_bounds__(512) void attn_fused_kernel(
        const unsigned short* __restrict__ qThi, const unsigned short* __restrict__ qTlo,
        const unsigned short* __restrict__ V,
        const float* __restrict__ rowm, const float* __restrict__ rowinv,
        const float* __restrict__ H, float* __restrict__ T)
{
    __shared__ unsigned short Alds[2][128 * 64];
    __shared__ unsigned short Blds[2][32 * 64];
    __shared__ float cparts[8][16];
    const int tid = threadIdx.x;
    const int b  = blockIdx.y;
    const int j0 = blockIdx.x * 32;
    const int lane = tid & 63;
    const int w = tid >> 6;
    const int g = lane >> 4;
    const int l15 = lane & 15;
    const int jsub = w & 1;
    const int tE = w >> 1;
    const int jl = jsub * 16 + l15;
    const int cb = (w >> 1) * 32;
    const int jb = jsub * 16;
    const int vc = tid >> 3, vslot = tid & 7;
    const int vc1 = (tid + 512) >> 3, vslot1 = (tid + 512) & 7;
    const bf16x8 bhi = *reinterpret_cast<const bf16x8*>(&qThi[((size_t)b * NPTS + j0 + jl) * 32 + g * 8]);
    const bf16x8 blo = *reinterpret_cast<const bf16x8*>(&qTlo[((size_t)b * NPTS + j0 + jl) * 32 + g * 8]);
    f32x4 acc[2];
    acc[0] = (f32x4){0.f, 0.f, 0.f, 0.f};
    acc[1] = (f32x4){0.f, 0.f, 0.f, 0.f};
    float csum = 0.f;

    float4 vreg0 = ld4((const float*)(V + ((size_t)(b * 128 + vc)) * NPTS + vslot * 8));
    float4 vreg1 = ld4((const float*)(V + ((size_t)(b * 128 + vc1)) * NPTS + vslot1 * 8));
    bf16x8 pahi = *reinterpret_cast<const bf16x8*>(&qThi[((size_t)b * NPTS + tE * 16 + l15) * 32 + g * 8]);
    bf16x8 palo = *reinterpret_cast<const bf16x8*>(&qTlo[((size_t)b * NPTS + tE * 16 + l15) * 32 + g * 8]);
    float4 pmv = ld4(&rowm[(size_t)b * NPTS + tE * 16 + g * 4]);
    float4 psv = ld4(&rowinv[(size_t)b * NPTS + tE * 16 + g * 4]);

    int p = 0;
    for (int i0 = 0; i0 < NPTS; i0 += 64) {
        {
            int sl = vslot ^ (vc & 7);
            *reinterpret_cast<float4*>(&Alds[p][vc * 64 + sl * 8]) = vreg0;
            sl = vslot1 ^ (vc1 & 7);
            *reinterpret_cast<float4*>(&Alds[p][vc1 * 64 + sl * 8]) = vreg1;
        }
        {
            f32x4 e4 = {0.f, 0.f, 0.f, 0.f};
            e4 = __builtin_amdgcn_mfma_f32_16x16x32_bf16(palo, bhi, e4, 0, 0, 0);
            e4 = __builtin_amdgcn_mfma_f32_16x16x32_bf16(pahi, blo, e4, 0, 0, 0);
            e4 = __builtin_amdgcn_mfma_f32_16x16x32_bf16(pahi, bhi, e4, 0, 0, 0);
            float p0 = __expf(e4[0] - pmv.x) * psv.x;
            float p1 = __expf(e4[1] - pmv.y) * psv.y;
            float p2 = __expf(e4[2] - pmv.z) * psv.z;
            float p3 = __expf(e4[3] - pmv.w) * psv.w;
            csum += p0 + p1 + p2 + p3;
            int il = tE * 16 + g * 4;
            int sl = (il >> 3) ^ (jl & 7);
            ull pk = (ull)f2bf(p0) | ((ull)f2bf(p1) << 16) |
                     ((ull)f2bf(p2) << 32) | ((ull)f2bf(p3) << 48);
            *reinterpret_cast<ull*>(&Blds[p][jl * 64 + sl * 8 + (il & 7)]) = pk;
        }
        {
            int i0n = (i0 + 64) & (NPTS - 1);
            vreg0 = ld4((const float*)(V + ((size_t)(b * 128 + vc)) * NPTS + i0n + vslot * 8));
            vreg1 = ld4((const float*)(V + ((size_t)(b * 128 + vc1)) * NPTS + i0n + vslot1 * 8));
            pahi = *reinterpret_cast<const bf16x8*>(&qThi[((size_t)b * NPTS + i0n + tE * 16 + l15) * 32 + g * 8]);
            palo = *reinterpret_cast<const bf16x8*>(&qTlo[((size_t)b * NPTS + i0n + tE * 16 + l15) * 32 + g * 8]);
            pmv = ld4(&rowm[(size_t)b * NPTS + i0n + tE * 16 + g * 4]);
            psv = ld4(&rowinv[(size_t)b * NPTS + i0n + tE * 16 + g * 4]);
        }
        __syncthreads();
        #pragma unroll
        for (int ks = 0; ks < 2; ++ks) {
            int j = jb + l15;
            int slb = (ks * 4 + g) ^ (j & 7);
            bf16x8 bfr = *reinterpret_cast<bf16x8*>(&Blds[p][j * 64 + slb * 8]);
            #pragma unroll
            for (int fa = 0; fa < 2; ++fa) {
                int c = cb + fa * 16 + l15;
                int sla = (ks * 4 + g) ^ (c & 7);
                bf16x8 afr = *reinterpret_cast<bf16x8*>(&Alds[p][c * 64 + sla * 8]);
                acc[fa] = __builtin_amdgcn_mfma_f32_16x16x32_bf16(afr, bfr, acc[fa], 0, 0, 0);
            }
        }
        p ^= 1;
    }
    csum += __shfl_xor(csum, 16, 64);
    csum += __shfl_xor(csum, 32, 64);
    if (lane < 16) cparts[w][l15] = csum;
    __syncthreads();
    float cs = cparts[jsub][l15] + cparts[jsub + 2][l15]
             + cparts[jsub + 4][l15] + cparts[jsub + 6][l15];
    float inv = 1.f / (1e-9f + cs);
    int jg_ = j0 + jb + l15;
    #pragma unroll
    for (int fa = 0; fa < 2; ++fa) {
        #pragma unroll
        for (int r = 0; r < 4; ++r) {
            int c = cb + fa * 16 + g * 4 + r;
            size_t base = ((size_t)(b * 128 + c)) * NPTS + jg_;
            T[base] = H[base] - acc[fa][r] * inv;
        }
    }
}

// ---------------------------------------------------------------------------
// Cooperative fused kernel: phase 1 = rowstats for rows j0..j0+31 (this WG's
// slice), grid.sync, phase 2 = R5 attn body. grid (64, NBAT), 512 threads.
// ---------------------------------------------------------------------------
__global__ __launch_bounds__(512) void rowstats_attn_kernel(
        const unsigned short* __restrict__ qThi, const unsigned short* __restrict__ qTlo,
        const unsigned short* __restrict__ V,
        float* __restrict__ rowm, float* __restrict__ rowinv,
        const float* __restrict__ H, float* __restrict__ T)
{
    __shared__ unsigned short Alds[2][128 * 64];
    __shared__ unsigned short Blds[2][32 * 64];
    __shared__ float cparts[8][16];
    __shared__ float pmw[8][16];
    __shared__ float psw[8][16];
    const int tid = threadIdx.x;
    const int b  = blockIdx.y;
    const int j0 = blockIdx.x * 32;
    const int lane = tid & 63;
    const int w = tid >> 6;
    const int g = lane >> 4;
    const int l15 = lane & 15;

    // ---- phase 1: row softmax stats for rows j0..j0+31 ----
    {
        const int rg = w & 1;        // row group (16 rows each)
        const int ch = w >> 1;       // j-chunk (512 j each)
        const int iR = j0 + rg * 16 + l15;
        const bf16x8 rbh = *reinterpret_cast<const bf16x8*>(&qThi[((size_t)b * NPTS + iR) * 32 + g * 8]);
        const bf16x8 rbl = *reinterpret_cast<const bf16x8*>(&qTlo[((size_t)b * NPTS + iR) * 32 + g * 8]);
        float m = -1e30f, s = 0.f;
        for (int t2 = ch * 32; t2 < ch * 32 + 32; ++t2) {
            int jr = t2 * 16 + l15;
            const bf16x8 ahi = *reinterpret_cast<const bf16x8*>(&qThi[((size_t)b * NPTS + jr) * 32 + g * 8]);
            const bf16x8 alo = *reinterpret_cast<const bf16x8*>(&qTlo[((size_t)b * NPTS + jr) * 32 + g * 8]);
            f32x4 e4 = {0.f, 0.f, 0.f, 0.f};
            e4 = __builtin_amdgcn_mfma_f32_16x16x32_bf16(alo, rbh, e4, 0, 0, 0);
            e4 = __builtin_amdgcn_mfma_f32_16x16x32_bf16(ahi, rbl, e4, 0, 0, 0);
            e4 = __builtin_amdgcn_mfma_f32_16x16x32_bf16(ahi, rbh, e4, 0, 0, 0);
            float tm = fmaxf(fmaxf(e4[0], e4[1]), fmaxf(e4[2], e4[3]));
            float nm = fmaxf(m, tm);
            s *= __expf(m - nm);
            m = nm;
            s += __expf(e4[0] - m) + __expf(e4[1] - m) + __expf(e4[2] - m) + __expf(e4[3] - m);
        }
        #pragma unroll
        for (int o = 16; o <= 32; o <<= 1) {
            float om = __shfl_xor(m, o, 64);
            float os = __shfl_xor(s, o, 64);
            float nm = fmaxf(m, om);
            s = s * __expf(m - nm) + os * __expf(om - nm);
            m = nm;
        }
        if (lane < 16) { pmw[w][l15] = m; psw[w][l15] = s; }
        __syncthreads();
        if (tid < 32) {
            int rgx = tid >> 4, l = tid & 15;
            float ma = pmw[rgx][l],     mb = pmw[rgx + 2][l];
            float mc = pmw[rgx + 4][l], md = pmw[rgx + 6][l];
            float mf = fmaxf(fmaxf(ma, mb), fmaxf(mc, md));
            float sf = psw[rgx][l] * __expf(ma - mf) + psw[rgx + 2][l] * __expf(mb - mf)
                     + psw[rgx + 4][l] * __expf(mc - mf) + psw[rgx + 6][l] * __expf(md - mf);
            rowm[(size_t)b * NPTS + j0 + tid] = mf;
            rowinv[(size_t)b * NPTS + j0 + tid] = 1.f / sf;
        }
        __threadfence();
        cg::this_grid().sync();
    }

    // ---- phase 2: attention (R5 body) ----
    const int jsub = w & 1;
    const int tE = w >> 1;
    const int jl = jsub * 16 + l15;
    const int cb = (w >> 1) * 32;
    const int jb = jsub * 16;
    const int vc = tid >> 3, vslot = tid & 7;
    const int vc1 = (tid + 512) >> 3, vslot1 = (tid + 512) & 7;
    const bf16x8 bhi = *reinterpret_cast<const bf16x8*>(&qThi[((size_t)b * NPTS + j0 + jl) * 32 + g * 8]);
    const bf16x8 blo = *reinterpret_cast<const bf16x8*>(&qTlo[((size_t)b * NPTS + j0 + jl) * 32 + g * 8]);
    f32x4 acc[2];
    acc[0] = (f32x4){0.f, 0.f, 0.f, 0.f};
    acc[1] = (f32x4){0.f, 0.f, 0.f, 0.f};
    float csum = 0.f;

    float4 vreg0 = ld4((const float*)(V + ((size_t)(b * 128 + vc)) * NPTS + vslot * 8));
    float4 vreg1 = ld4((const float*)(V + ((size_t)(b * 128 + vc1)) * NPTS + vslot1 * 8));
    bf16x8 pahi = *reinterpret_cast<const bf16x8*>(&qThi[((size_t)b * NPTS + tE * 16 + l15) * 32 + g * 8]);
    bf16x8 palo = *reinterpret_cast<const bf16x8*>(&qTlo[((size_t)b * NPTS + tE * 16 + l15) * 32 + g * 8]);
    float4 pmv = ld4(&rowm[(size_t)b * NPTS + tE * 16 + g * 4]);
    float4 psv = ld4(&rowinv[(size_t)b * NPTS + tE * 16 + g * 4]);

    int p = 0;
    for (int i0 = 0; i0 < NPTS; i0 += 64) {
        {
            int sl = vslot ^ (vc & 7);
            *reinterpret_cast<float4*>(&Alds[p][vc * 64 + sl * 8]) = vreg0;
            sl = vslot1 ^ (vc1 & 7);
            *reinterpret_cast<float4*>(&Alds[p][vc1 * 64 + sl * 8]) = vreg1;
        }
        {
            f32x4 e4 = {0.f, 0.f, 0.f, 0.f};
            e4 = __builtin_amdgcn_mfma_f32_16x16x32_bf16(palo, bhi, e4, 0, 0, 0);
            e4 = __builtin_amdgcn_mfma_f32_16x16x32_bf16(pahi, blo, e4, 0, 0, 0);
            e4 = __builtin_amdgcn_mfma_f32_16x16x32_bf16(pahi, bhi, e4, 0, 0, 0);
            float p0 = __expf(e4[0] - pmv.x) * psv.x;
            float p1 = __expf(e4[1] - pmv.y) * psv.y;
            float p2 = __expf(e4[2] - pmv.z) * psv.z;
            float p3 = __expf(e4[3] - pmv.w) * psv.w;
            csum += p0 + p1 + p2 + p3;
            int il = tE * 16 + g * 4;
            int sl = (il >> 3) ^ (jl & 7);
            ull pk = (ull)f2bf(p0) | ((ull)f2bf(p1) << 16) |
                     ((ull)f2bf(p2) << 32) | ((ull)f2bf(p3) << 48);
            *reinterpret_cast<ull*>(&Blds[p][jl * 64 + sl * 8 + (il & 7)]) = pk;
        }
        {
            int i0n = (i0 + 64) & (NPTS - 1);
            vreg0 = ld4((const float*)(V + ((size_t)(b * 128 + vc)) * NPTS + i0n + vslot * 8));
            vreg1 = ld4((const float*)(V + ((size_t)(b * 128 + vc1)) * NPTS + i0n + vslot1 * 8));
            pahi = *reinterpret_cast<const bf16x8*>(&qThi[((size_t)b * NPTS + i0n + tE * 16 + l15) * 32 + g * 8]);
            palo = *reinterpret_cast<const bf16x8*>(&qTlo[((size_t)b * NPTS + i0n + tE * 16 + l15) * 32 + g * 8]);
            pmv = ld4(&rowm[(size_t)b * NPTS + i0n + tE * 16 + g * 4]);
            psv = ld4(&rowinv[(size_t)b * NPTS + i0n + tE * 16 + g * 4]);
        }
        __syncthreads();
        #pragma unroll
        for (int ks = 0; ks < 2; ++ks) {
            int j = jb + l15;
            int slb = (ks * 4 + g) ^ (j & 7);
            bf16x8 bfr = *reinterpret_cast<bf16x8*>(&Blds[p][j * 64 + slb * 8]);
            #pragma unroll
            for (int fa = 0; fa < 2; ++fa) {
                int c = cb + fa * 16 + l15;
                int sla = (ks * 4 + g) ^ (c & 7);
                bf16x8 afr = *reinterpret_cast<bf16x8*>(&Alds[p][c * 64 + sla * 8]);
                acc[fa] = __builtin_amdgcn_mfma_f32_16x16x32_bf16(afr, bfr, acc[fa], 0, 0, 0);
            }
        }
        p ^= 1;
    }
    csum += __shfl_xor(csum, 16, 64);
    csum += __shfl_xor(csum, 32, 64);
    if (lane < 16) cparts[w][l15] = csum;
    __syncthreads();
    float cs = cparts[jsub][l15] + cparts[jsub + 2][l15]
             + cparts[jsub + 4][l15] + cparts[jsub + 6][l15];
    float inv = 1.f / (1e-9f + cs);
    int jg_ = j0 + jb + l15;
    #pragma unroll
    for (int fa = 0; fa < 2; ++fa) {
        #pragma unroll
        for (int r = 0; r < 4; ++r) {
            int c = cb + fa * 16 + g * 4 + r;
            size_t base = ((size_t)(b * 128 + c)) * NPTS + jg_;
            T[base] = H[base] - acc[fa][r] * inv;
        }
    }
}

// partial per-(c,b) sums: grid (C, NBAT)   (R5 version)
__global__ __launch_bounds__(256) void bn_part_kernel(const float* __restrict__ X,
        int C, float* __restrict__ part)
{
    __shared__ float red[4];
    const int c = blockIdx.x;
    const int b = blockIdx.y;
    const int tid = threadIdx.x;
    const float* p = &X[((size_t)(b * C + c)) * NPTS];
    float s = 0.f, s2 = 0.f;
    #pragma unroll
    for (int l = 0; l < 2; ++l) {
        float4 v = ld4(&p[(tid + 256 * l) * 4]);
        s  += v.x + v.y + v.z + v.w;
        s2 += v.x * v.x + v.y * v.y + v.z * v.z + v.w * v.w;
    }
    s  = blk_red_sum(s, red);
    s2 = blk_red_sum(s2, red);
    if (tid == 0) {
        part[b * C + c] = s;
        part[NBAT * C + b * C + c] = s2;
    }
}

__device__ __forceinline__ void bn_finalize(const float* part, int C, int c,
                                            float& mean, float& istd)
{
    float s = 0.f, s2 = 0.f;
    #pragma unroll
    for (int b = 0; b < NBAT; ++b) {
        s  += part[b * C + c];
        s2 += part[NBAT * C + b * C + c];
    }
    const float invn = 1.f / (NBAT * NPTS);
    mean = s * invn;
    float var = s2 * invn - mean * mean;
    istd = rsqrtf(var + 1e-5f);
}

__global__ __launch_bounds__(256) void bn_apply_kernel(const float* __restrict__ X,
        const float* __restrict__ g, const float* __restrict__ beta,
        const float* __restrict__ part, int C, float* __restrict__ out)
{
    const int bc = blockIdx.y;
    const int c = bc % C;
    const int n = blockIdx.x * 1024 + threadIdx.x * 4;
    float mean, is;
    bn_finalize(part, C, c, mean, is);
    const float ga = g[c] * is;
    const float be = beta[c] - mean * ga;
    float4 v = ld4(&X[(size_t)bc * NPTS + n]);
    float4 o;
    o.x = fmaxf(fmaf(ga, v.x, be), 0.f);
    o.y = fmaxf(fmaf(ga, v.y, be), 0.f);
    o.z = fmaxf(fmaf(ga, v.z, be), 0.f);
    o.w = fmaxf(fmaf(ga, v.w, be), 0.f);
    st4(&out[(size_t)bc * NPTS + n], o);
}

__global__ __launch_bounds__(256) void bn_res_kernel(const float* __restrict__ Y,
        const float* __restrict__ g, const float* __restrict__ beta,
        const float* __restrict__ part, float* __restrict__ H,
        float* __restrict__ out, int blk)
{
    const int bc = blockIdx.y;
    const int c = bc & 127;
    const int b = bc >> 7;
    const int n = blockIdx.x * 1024 + threadIdx.x * 4;
    float mean, is;
    bn_finalize(part, 128, c, mean, is);
    const float ga = g[c] * is;
    const float be = beta[c] - mean * ga;
    float4 yv = ld4(&Y[(size_t)bc * NPTS + n]);
    float4 hv = ld4(&H[(size_t)bc * NPTS + n]);
    float4 o;
    o.x = hv.x + fmaxf(fmaf(ga, yv.x, be), 0.f);
    o.y = hv.y + fmaxf(fmaf(ga, yv.y, be), 0.f);
    o.z = hv.z + fmaxf(fmaf(ga, yv.z, be), 0.f);
    o.w = hv.w + fmaxf(fmaf(ga, yv.w, be), 0.f);
    st4(&H[(size_t)bc * NPTS + n], o);
    st4(&out[((size_t)(b * 512 + blk * 128 + c)) * NPTS + n], o);
}

extern "C" void kernel_launch(void* const* d_in, const int* in_sizes, int n_in,
                              void* d_out, int out_size, void* d_ws, size_t ws_size,
                              hipStream_t stream)
{
    const float* x   = (const float*)d_in[0];
    const float* W1  = (const float*)d_in[1];
    const float* g1  = (const float*)d_in[2];
    const float* b1  = (const float*)d_in[3];
    const float* W2  = (const float*)d_in[4];
    const float* g2  = (const float*)d_in[5];
    const float* b2  = (const float*)d_in[6];
    const float* Wqk = (const float*)d_in[7];
    const float* Wv  = (const float*)d_in[8];
    const float* bv  = (const float*)d_in[9];
    const float* Wt  = (const float*)d_in[10];
    const float* bt  = (const float*)d_in[11];
    const float* gn  = (const float*)d_in[12];
    const float* bnb = (const float*)d_in[13];
    float* out = (float*)d_out;

    float* ws = (float*)d_ws;
    size_t off = 0;
    auto alloc = [&](size_t n) { float* p = ws + off; off += n; return p; };
    float* h      = alloc((size_t)NBAT * 128 * NPTS);
    float* t      = alloc((size_t)NBAT * 128 * NPTS);
    float* y      = alloc((size_t)NBAT * 128 * NPTS);
    float* part   = alloc(2 * NBAT * 128);
    float* rowm   = alloc((size_t)NBAT * NPTS);
    float* rowinv = alloc((size_t)NBAT * NPTS);
    unsigned short* vb   = (unsigned short*)alloc((size_t)NBAT * 128 * NPTS / 2);
    unsigned short* qThi = (unsigned short*)alloc((size_t)NBAT * NPTS * 32 / 2);
    unsigned short* qTlo = (unsigned short*)alloc((size_t)NBAT * NPTS * 32 / 2);

    // stem: h = relu(bn(W2 @ relu(bn(W1 @ x))))
    lin_mfma_kernel<64, 64, 64, 32, 0, false><<<dim3(64, 1, NBAT), 256, 0, stream>>>(
        W1, x, nullptr, y, nullptr);
    bn_part_kernel<<<dim3(64, NBAT), 256, 0, stream>>>(y, 64, part);
    bn_apply_kernel<<<dim3(2, NBAT * 64), 256, 0, stream>>>(y, g1, b1, part, 64, t);
    lin_mfma_kernel<64, 128, 64, 32, 0, false><<<dim3(64, 2, NBAT), 256, 0, stream>>>(
        W2, t, nullptr, y, nullptr);
    bn_part_kernel<<<dim3(128, NBAT), 256, 0, stream>>>(y, 128, part);
    bn_apply_kernel<<<dim3(2, NBAT * 128), 256, 0, stream>>>(y, g2, b2, part, 128, h);

    for (int blk = 0; blk < 4; ++blk) {
        lin_mfma_kernel<128, 32, 32, 32, 2, false><<<dim3(64, 1, NBAT), 256, 0, stream>>>(
            Wqk + (size_t)blk * 32 * 128, h, nullptr, qThi, qTlo);
        lin_mfma_kernel<128, 128, 64, 32, 1, true><<<dim3(64, 2, NBAT), 256, 0, stream>>>(
            Wv + (size_t)blk * 128 * 128, h, bv + blk * 128, vb, nullptr);
        {
            const unsigned short* a0 = qThi;
            const unsigned short* a1 = qTlo;
            const unsigned short* a2 = vb;
            float* a3 = rowm;
            float* a4 = rowinv;
            const float* a5 = h;
            float* a6 = t;
            void* ka[7] = { (void*)&a0, (void*)&a1, (void*)&a2, (void*)&a3,
                            (void*)&a4, (void*)&a5, (void*)&a6 };
            hipError_t err = hipLaunchCooperativeKernel(
                reinterpret_cast<const void*>(&rowstats_attn_kernel),
                dim3(64, NBAT), dim3(512), ka, 0, stream);
            if (err != hipSuccess) {
                rowstats_fused_kernel<<<dim3(128, NBAT), 256, 0, stream>>>(
                    qThi, qTlo, rowm, rowinv);
                attn_fused_kernel<<<dim3(64, NBAT), 512, 0, stream>>>(
                    qThi, qTlo, vb, rowm, rowinv, h, t);
            }
        }
        lin_mfma_kernel<128, 128, 64, 32, 0, true><<<dim3(64, 2, NBAT), 256, 0, stream>>>(
            Wt + (size_t)blk * 128 * 128, t, bt + blk * 128, y, nullptr);
        bn_part_kernel<<<dim3(128, NBAT), 256, 0, stream>>>(y, 128, part);
        bn_res_kernel<<<dim3(2, NBAT * 128), 256, 0, stream>>>(
            y, gn + blk * 128, bnb + blk * 128, part, h, out, blk);
    }
}

// Round 10
// 364.524 us; speedup vs baseline: 2.0372x; 2.0372x over previous
//
#include <hip/hip_runtime.h>
#include <cstdint>
#include <cstddef>

#define NPTS 2048
#define NBAT 8

typedef unsigned long long ull;
typedef __attribute__((ext_vector_type(8))) short bf16x8;
typedef __attribute__((ext_vector_type(4))) float f32x4;

__device__ __forceinline__ float4 ld4(const float* p){ return *reinterpret_cast<const float4*>(p); }
__device__ __forceinline__ void st4(float* p, float4 v){ *reinterpret_cast<float4*>(p) = v; }
__device__ __forceinline__ unsigned short f2bf(float f){
    unsigned int u = __float_as_uint(f);
    u += 0x7FFFu + ((u >> 16) & 1u);
    return (unsigned short)(u >> 16);
}
__device__ __forceinline__ float bf2f(unsigned short h){
    return __uint_as_float(((unsigned int)h) << 16);
}

// LDS-only barrier: waits local ds ops, leaves global loads (vmcnt) in flight.
#define BAR_LDS() do { asm volatile("s_waitcnt lgkmcnt(0)" ::: "memory"); \
                       __builtin_amdgcn_s_barrier(); } while (0)

__device__ __forceinline__ float blk_red_sum(float v, float* red){
    #pragma unroll
    for (int o = 32; o > 0; o >>= 1) v += __shfl_xor(v, o, 64);
    int wid = threadIdx.x >> 6;
    if ((threadIdx.x & 63) == 0) red[wid] = v;
    __syncthreads();
    v = red[0] + red[1] + red[2] + red[3];
    __syncthreads();
    return v;
}

// ---------------------------------------------------------------------------
// MFMA linear (R5 version): out[b,d,n] = sum_c W[d,c]*X[b,c,n] (+bias)
// MODE: 0=fp32 out, 1=bf16 out, 2=qT hi/lo out.
// ---------------------------------------------------------------------------
template<int CIN, int COUT, int TD, int TN, int MODE, bool BIAS>
__global__ __launch_bounds__(256) void lin_mfma_kernel(
        const float* __restrict__ W, const float* __restrict__ X,
        const float* __restrict__ bias, void* __restrict__ outv,
        void* __restrict__ outv2)
{
    constexpr int WD  = TD / 16;
    constexpr int NPW = TN * WD / 4;
    constexpr int FB  = NPW / 16;
    constexpr int KS  = CIN / 32;
    __shared__ unsigned short Xhi[TN * CIN];
    __shared__ unsigned short Xlo[TN * CIN];
    const int tid = threadIdx.x;
    const int lane = tid & 63;
    const int w = tid >> 6;
    const int g = lane >> 4;
    const int l15 = lane & 15;
    const int b = blockIdx.z;
    const int d0 = blockIdx.y * TD;
    const int n0 = blockIdx.x * TN;
    const int dw = (w % WD) * 16;
    const int nw = (w / WD) * NPW;

    bf16x8 Whi[KS], Wlo[KS];
    {
        const int d = d0 + dw + l15;
        #pragma unroll
        for (int ks = 0; ks < KS; ++ks) {
            float4 a = ld4(&W[(size_t)d * CIN + ks * 32 + g * 8]);
            float4 bq = ld4(&W[(size_t)d * CIN + ks * 32 + g * 8 + 4]);
            float vv[8] = {a.x, a.y, a.z, a.w, bq.x, bq.y, bq.z, bq.w};
            bf16x8 h8, l8;
            #pragma unroll
            for (int e = 0; e < 8; ++e) {
                unsigned short hh = f2bf(vv[e]);
                h8[e] = (short)hh;
                l8[e] = (short)f2bf(vv[e] - bf2f(hh));
            }
            Whi[ks] = h8; Wlo[ks] = l8;
        }
    }
    constexpr int TN4 = TN / 4;
    constexpr int NF = (TN * CIN) / 1024;
    #pragma unroll
    for (int f = 0; f < NF; ++f) {
        int idx = tid + 256 * f;
        int c = idx / TN4;
        int n = (idx % TN4) * 4;
        float4 xv = ld4(&X[((size_t)(b * CIN + c)) * NPTS + n0 + n]);
        float vv[4] = {xv.x, xv.y, xv.z, xv.w};
        #pragma unroll
        for (int j2 = 0; j2 < 4; ++j2) {
            int nn = n + j2;
            int cp = (c + nn * 8) & (CIN - 1);
            unsigned short hh = f2bf(vv[j2]);
            Xhi[nn * CIN + cp] = hh;
            Xlo[nn * CIN + cp] = f2bf(vv[j2] - bf2f(hh));
        }
    }
    __syncthreads();

    f32x4 acc[FB];
    #pragma unroll
    for (int fb = 0; fb < FB; ++fb) acc[fb] = (f32x4){0.f, 0.f, 0.f, 0.f};
    #pragma unroll
    for (int ks = 0; ks < KS; ++ks) {
        #pragma unroll
        for (int fb = 0; fb < FB; ++fb) {
            int n = nw + fb * 16 + l15;
            int cp = (ks * 32 + g * 8 + n * 8) & (CIN - 1);
            bf16x8 xh = *reinterpret_cast<bf16x8*>(&Xhi[n * CIN + cp]);
            bf16x8 xl = *reinterpret_cast<bf16x8*>(&Xlo[n * CIN + cp]);
            acc[fb] = __builtin_amdgcn_mfma_f32_16x16x32_bf16(Wlo[ks], xh, acc[fb], 0, 0, 0);
            acc[fb] = __builtin_amdgcn_mfma_f32_16x16x32_bf16(Whi[ks], xl, acc[fb], 0, 0, 0);
            acc[fb] = __builtin_amdgcn_mfma_f32_16x16x32_bf16(Whi[ks], xh, acc[fb], 0, 0, 0);
        }
    }
    const int dbase = d0 + dw + g * 4;
    float bb[4] = {0.f, 0.f, 0.f, 0.f};
    if (BIAS) {
        float4 b4 = ld4(&bias[dbase]);
        bb[0] = b4.x; bb[1] = b4.y; bb[2] = b4.z; bb[3] = b4.w;
    }
    #pragma unroll
    for (int fb = 0; fb < FB; ++fb) {
        int ncol = n0 + nw + fb * 16 + l15;
        if (MODE == 2) {
            unsigned short* qh = (unsigned short*)outv;
            unsigned short* ql = (unsigned short*)outv2;
            ushort4 hh, ll;
            float q0 = acc[fb][0], q1 = acc[fb][1], q2 = acc[fb][2], q3 = acc[fb][3];
            hh.x = f2bf(q0); ll.x = f2bf(q0 - bf2f(hh.x));
            hh.y = f2bf(q1); ll.y = f2bf(q1 - bf2f(hh.y));
            hh.z = f2bf(q2); ll.z = f2bf(q2 - bf2f(hh.z));
            hh.w = f2bf(q3); ll.w = f2bf(q3 - bf2f(hh.w));
            *reinterpret_cast<ushort4*>(&qh[((size_t)b * NPTS + ncol) * 32 + dbase]) = hh;
            *reinterpret_cast<ushort4*>(&ql[((size_t)b * NPTS + ncol) * 32 + dbase]) = ll;
        } else if (MODE == 1) {
            unsigned short* ob = (unsigned short*)outv;
            #pragma unroll
            for (int r = 0; r < 4; ++r)
                ob[((size_t)(b * COUT + dbase + r)) * NPTS + ncol] = f2bf(acc[fb][r] + bb[r]);
        } else {
            float* ob = (float*)outv;
            #pragma unroll
            for (int r = 0; r < 4; ++r)
                ob[((size_t)(b * COUT + dbase + r)) * NPTS + ncol] = acc[fb][r] + bb[r];
        }
    }
}

// row softmax stats via on-the-fly e = qT q (R5 version). grid (NPTS/16, NBAT).
__global__ __launch_bounds__(256) void rowstats_fused_kernel(
        const unsigned short* __restrict__ qThi, const unsigned short* __restrict__ qTlo,
        float* __restrict__ rowm, float* __restrict__ rowinv)
{
    __shared__ float pm[4][16];
    __shared__ float ps[4][16];
    const int lane = threadIdx.x & 63;
    const int w = threadIdx.x >> 6;
    const int b = blockIdx.y;
    const int i0 = blockIdx.x * 16;
    const int g = lane >> 4;
    const int l15 = lane & 15;
    const int iR = i0 + l15;
    const bf16x8 bhi = *reinterpret_cast<const bf16x8*>(&qThi[((size_t)b * NPTS + iR) * 32 + g * 8]);
    const bf16x8 blo = *reinterpret_cast<const bf16x8*>(&qTlo[((size_t)b * NPTS + iR) * 32 + g * 8]);
    float m = -1e30f, s = 0.f;
    for (int t = w * 32; t < w * 32 + 32; ++t) {
        int jr = t * 16 + l15;
        const bf16x8 ahi = *reinterpret_cast<const bf16x8*>(&qThi[((size_t)b * NPTS + jr) * 32 + g * 8]);
        const bf16x8 alo = *reinterpret_cast<const bf16x8*>(&qTlo[((size_t)b * NPTS + jr) * 32 + g * 8]);
        f32x4 e4 = {0.f, 0.f, 0.f, 0.f};
        e4 = __builtin_amdgcn_mfma_f32_16x16x32_bf16(alo, bhi, e4, 0, 0, 0);
        e4 = __builtin_amdgcn_mfma_f32_16x16x32_bf16(ahi, blo, e4, 0, 0, 0);
        e4 = __builtin_amdgcn_mfma_f32_16x16x32_bf16(ahi, bhi, e4, 0, 0, 0);
        float tm = fmaxf(fmaxf(e4[0], e4[1]), fmaxf(e4[2], e4[3]));
        float nm = fmaxf(m, tm);
        s *= __expf(m - nm);
        m = nm;
        s += __expf(e4[0] - m) + __expf(e4[1] - m) + __expf(e4[2] - m) + __expf(e4[3] - m);
    }
    #pragma unroll
    for (int o = 16; o <= 32; o <<= 1) {
        float om = __shfl_xor(m, o, 64);
        float os = __shfl_xor(s, o, 64);
        float nm = fmaxf(m, om);
        s = s * __expf(m - nm) + os * __expf(om - nm);
        m = nm;
    }
    if (lane < 16) { pm[w][l15] = m; ps[w][l15] = s; }
    __syncthreads();
    if (threadIdx.x < 16) {
        float m0 = pm[0][threadIdx.x], m1 = pm[1][threadIdx.x];
        float m2 = pm[2][threadIdx.x], m3 = pm[3][threadIdx.x];
        float mf = fmaxf(fmaxf(m0, m1), fmaxf(m2, m3));
        float sf = ps[0][threadIdx.x] * __expf(m0 - mf)
                 + ps[1][threadIdx.x] * __expf(m1 - mf)
                 + ps[2][threadIdx.x] * __expf(m2 - mf)
                 + ps[3][threadIdx.x] * __expf(m3 - mf);
        rowm[(size_t)b * NPTS + i0 + threadIdx.x] = mf;
        rowinv[(size_t)b * NPTS + i0 + threadIdx.x] = 1.f / sf;
    }
}

// Fused attention: R5 structure (dbuf LDS, reg prefetch, 1 barrier/step) with
// the in-loop barrier replaced by an LDS-only wait so the global prefetch
// stays in flight across it and drains under PV. No setprio.
__global__ __launch_bounds__(512) void attn_fused_kernel(
        const unsigned short* __restrict__ qThi, const unsigned short* __restrict__ qTlo,
        const unsigned short* __restrict__ V,
        const float* __restrict__ rowm, const float* __restrict__ rowinv,
        const float* __restrict__ H, float* __restrict__ T)
{
    __shared__ unsigned short Alds[2][128 * 64];
    __shared__ unsigned short Blds[2][32 * 64];
    __shared__ float cparts[8][16];
    const int tid = threadIdx.x;
    const int b  = blockIdx.y;
    const int j0 = blockIdx.x * 32;
    const int lane = tid & 63;
    const int w = tid >> 6;
    const int g = lane >> 4;
    const int l15 = lane & 15;
    const int jsub = w & 1;
    const int tE = w >> 1;
    const int jl = jsub * 16 + l15;
    const int cb = (w >> 1) * 32;
    const int jb = jsub * 16;
    const int vc = tid >> 3, vslot = tid & 7;
    const int vc1 = (tid + 512) >> 3, vslot1 = (tid + 512) & 7;
    const bf16x8 bhi = *reinterpret_cast<const bf16x8*>(&qThi[((size_t)b * NPTS + j0 + jl) * 32 + g * 8]);
    const bf16x8 blo = *reinterpret_cast<const bf16x8*>(&qTlo[((size_t)b * NPTS + j0 + jl) * 32 + g * 8]);
    f32x4 acc[2];
    acc[0] = (f32x4){0.f, 0.f, 0.f, 0.f};
    acc[1] = (f32x4){0.f, 0.f, 0.f, 0.f};
    float csum = 0.f;

    // prefetch for i0 = 0
    float4 vreg0 = ld4((const float*)(V + ((size_t)(b * 128 + vc)) * NPTS + vslot * 8));
    float4 vreg1 = ld4((const float*)(V + ((size_t)(b * 128 + vc1)) * NPTS + vslot1 * 8));
    bf16x8 pahi = *reinterpret_cast<const bf16x8*>(&qThi[((size_t)b * NPTS + tE * 16 + l15) * 32 + g * 8]);
    bf16x8 palo = *reinterpret_cast<const bf16x8*>(&qTlo[((size_t)b * NPTS + tE * 16 + l15) * 32 + g * 8]);
    float4 pmv = ld4(&rowm[(size_t)b * NPTS + tE * 16 + g * 4]);
    float4 psv = ld4(&rowinv[(size_t)b * NPTS + tE * 16 + g * 4]);

    int p = 0;
    for (int i0 = 0; i0 < NPTS; i0 += 64) {
        // commit prefetched V tile to Alds[p]
        {
            int sl = vslot ^ (vc & 7);
            *reinterpret_cast<float4*>(&Alds[p][vc * 64 + sl * 8]) = vreg0;
            sl = vslot1 ^ (vc1 & 7);
            *reinterpret_cast<float4*>(&Alds[p][vc1 * 64 + sl * 8]) = vreg1;
        }
        // e-compute from prefetched qT frags -> Blds[p]
        {
            f32x4 e4 = {0.f, 0.f, 0.f, 0.f};
            e4 = __builtin_amdgcn_mfma_f32_16x16x32_bf16(palo, bhi, e4, 0, 0, 0);
            e4 = __builtin_amdgcn_mfma_f32_16x16x32_bf16(pahi, blo, e4, 0, 0, 0);
            e4 = __builtin_amdgcn_mfma_f32_16x16x32_bf16(pahi, bhi, e4, 0, 0, 0);
            float p0 = __expf(e4[0] - pmv.x) * psv.x;
            float p1 = __expf(e4[1] - pmv.y) * psv.y;
            float p2 = __expf(e4[2] - pmv.z) * psv.z;
            float p3 = __expf(e4[3] - pmv.w) * psv.w;
            csum += p0 + p1 + p2 + p3;
            int il = tE * 16 + g * 4;
            int sl = (il >> 3) ^ (jl & 7);
            ull pk = (ull)f2bf(p0) | ((ull)f2bf(p1) << 16) |
                     ((ull)f2bf(p2) << 32) | ((ull)f2bf(p3) << 48);
            *reinterpret_cast<ull*>(&Blds[p][jl * 64 + sl * 8 + (il & 7)]) = pk;
        }
        // prefetch next step (loads stay in flight across the LDS-only barrier)
        {
            int i0n = (i0 + 64) & (NPTS - 1);
            vreg0 = ld4((const float*)(V + ((size_t)(b * 128 + vc)) * NPTS + i0n + vslot * 8));
            vreg1 = ld4((const float*)(V + ((size_t)(b * 128 + vc1)) * NPTS + i0n + vslot1 * 8));
            pahi = *reinterpret_cast<const bf16x8*>(&qThi[((size_t)b * NPTS + i0n + tE * 16 + l15) * 32 + g * 8]);
            palo = *reinterpret_cast<const bf16x8*>(&qTlo[((size_t)b * NPTS + i0n + tE * 16 + l15) * 32 + g * 8]);
            pmv = ld4(&rowm[(size_t)b * NPTS + i0n + tE * 16 + g * 4]);
            psv = ld4(&rowinv[(size_t)b * NPTS + i0n + tE * 16 + g * 4]);
        }
        BAR_LDS();
        // PV: 32c x 16j slice, K=64
        #pragma unroll
        for (int ks = 0; ks < 2; ++ks) {
            int j = jb + l15;
            int slb = (ks * 4 + g) ^ (j & 7);
            bf16x8 bfr = *reinterpret_cast<bf16x8*>(&Blds[p][j * 64 + slb * 8]);
            #pragma unroll
            for (int fa = 0; fa < 2; ++fa) {
                int c = cb + fa * 16 + l15;
                int sla = (ks * 4 + g) ^ (c & 7);
                bf16x8 afr = *reinterpret_cast<bf16x8*>(&Alds[p][c * 64 + sla * 8]);
                acc[fa] = __builtin_amdgcn_mfma_f32_16x16x32_bf16(afr, bfr, acc[fa], 0, 0, 0);
            }
        }
        p ^= 1;
    }
    csum += __shfl_xor(csum, 16, 64);
    csum += __shfl_xor(csum, 32, 64);
    if (lane < 16) cparts[w][l15] = csum;
    __syncthreads();
    float cs = cparts[jsub][l15] + cparts[jsub + 2][l15]
             + cparts[jsub + 4][l15] + cparts[jsub + 6][l15];
    float inv = 1.f / (1e-9f + cs);
    int jg_ = j0 + jb + l15;
    #pragma unroll
    for (int fa = 0; fa < 2; ++fa) {
        #pragma unroll
        for (int r = 0; r < 4; ++r) {
            int c = cb + fa * 16 + g * 4 + r;
            size_t base = ((size_t)(b * 128 + c)) * NPTS + jg_;
            T[base] = H[base] - acc[fa][r] * inv;
        }
    }
}

// partial per-(c,b) sums: grid (C, NBAT)
__global__ __launch_bounds__(256) void bn_part_kernel(const float* __restrict__ X,
        int C, float* __restrict__ part)
{
    __shared__ float red[4];
    const int c = blockIdx.x;
    const int b = blockIdx.y;
    const int tid = threadIdx.x;
    const float* p = &X[((size_t)(b * C + c)) * NPTS];
    float s = 0.f, s2 = 0.f;
    #pragma unroll
    for (int l = 0; l < 2; ++l) {
        float4 v = ld4(&p[(tid + 256 * l) * 4]);
        s  += v.x + v.y + v.z + v.w;
        s2 += v.x * v.x + v.y * v.y + v.z * v.z + v.w * v.w;
    }
    s  = blk_red_sum(s, red);
    s2 = blk_red_sum(s2, red);
    if (tid == 0) {
        part[b * C + c] = s;
        part[NBAT * C + b * C + c] = s2;
    }
}

__device__ __forceinline__ void bn_finalize(const float* part, int C, int c,
                                            float& mean, float& istd)
{
    float s = 0.f, s2 = 0.f;
    #pragma unroll
    for (int b = 0; b < NBAT; ++b) {
        s  += part[b * C + c];
        s2 += part[NBAT * C + b * C + c];
    }
    const float invn = 1.f / (NBAT * NPTS);
    mean = s * invn;
    float var = s2 * invn - mean * mean;
    istd = rsqrtf(var + 1e-5f);
}

__global__ __launch_bounds__(256) void bn_apply_kernel(const float* __restrict__ X,
        const float* __restrict__ g, const float* __restrict__ beta,
        const float* __restrict__ part, int C, float* __restrict__ out)
{
    const int bc = blockIdx.y;
    const int c = bc % C;
    const int n = blockIdx.x * 1024 + threadIdx.x * 4;
    float mean, is;
    bn_finalize(part, C, c, mean, is);
    const float ga = g[c] * is;
    const float be = beta[c] - mean * ga;
    float4 v = ld4(&X[(size_t)bc * NPTS + n]);
    float4 o;
    o.x = fmaxf(fmaf(ga, v.x, be), 0.f);
    o.y = fmaxf(fmaf(ga, v.y, be), 0.f);
    o.z = fmaxf(fmaf(ga, v.z, be), 0.f);
    o.w = fmaxf(fmaf(ga, v.w, be), 0.f);
    st4(&out[(size_t)bc * NPTS + n], o);
}

__global__ __launch_bounds__(256) void bn_res_kernel(const float* __restrict__ Y,
        const float* __restrict__ g, const float* __restrict__ beta,
        const float* __restrict__ part, float* __restrict__ H,
        float* __restrict__ out, int blk)
{
    const int bc = blockIdx.y;
    const int c = bc & 127;
    const int b = bc >> 7;
    const int n = blockIdx.x * 1024 + threadIdx.x * 4;
    float mean, is;
    bn_finalize(part, 128, c, mean, is);
    const float ga = g[c] * is;
    const float be = beta[c] - mean * ga;
    float4 yv = ld4(&Y[(size_t)bc * NPTS + n]);
    float4 hv = ld4(&H[(size_t)bc * NPTS + n]);
    float4 o;
    o.x = hv.x + fmaxf(fmaf(ga, yv.x, be), 0.f);
    o.y = hv.y + fmaxf(fmaf(ga, yv.y, be), 0.f);
    o.z = hv.z + fmaxf(fmaf(ga, yv.z, be), 0.f);
    o.w = hv.w + fmaxf(fmaf(ga, yv.w, be), 0.f);
    st4(&H[(size_t)bc * NPTS + n], o);
    st4(&out[((size_t)(b * 512 + blk * 128 + c)) * NPTS + n], o);
}

extern "C" void kernel_launch(void* const* d_in, const int* in_sizes, int n_in,
                              void* d_out, int out_size, void* d_ws, size_t ws_size,
                              hipStream_t stream)
{
    const float* x   = (const float*)d_in[0];
    const float* W1  = (const float*)d_in[1];
    const float* g1  = (const float*)d_in[2];
    const float* b1  = (const float*)d_in[3];
    const float* W2  = (const float*)d_in[4];
    const float* g2  = (const float*)d_in[5];
    const float* b2  = (const float*)d_in[6];
    const float* Wqk = (const float*)d_in[7];
    const float* Wv  = (const float*)d_in[8];
    const float* bv  = (const float*)d_in[9];
    const float* Wt  = (const float*)d_in[10];
    const float* bt  = (const float*)d_in[11];
    const float* gn  = (const float*)d_in[12];
    const float* bnb = (const float*)d_in[13];
    float* out = (float*)d_out;

    float* ws = (float*)d_ws;
    size_t off = 0;
    auto alloc = [&](size_t n) { float* p = ws + off; off += n; return p; };
    float* h      = alloc((size_t)NBAT * 128 * NPTS);
    float* t      = alloc((size_t)NBAT * 128 * NPTS);
    float* y      = alloc((size_t)NBAT * 128 * NPTS);
    float* part   = alloc(2 * NBAT * 128);
    float* rowm   = alloc((size_t)NBAT * NPTS);
    float* rowinv = alloc((size_t)NBAT * NPTS);
    unsigned short* vb   = (unsigned short*)alloc((size_t)NBAT * 128 * NPTS / 2);
    unsigned short* qThi = (unsigned short*)alloc((size_t)NBAT * NPTS * 32 / 2);
    unsigned short* qTlo = (unsigned short*)alloc((size_t)NBAT * NPTS * 32 / 2);

    // stem: h = relu(bn(W2 @ relu(bn(W1 @ x))))
    lin_mfma_kernel<64, 64, 64, 32, 0, false><<<dim3(64, 1, NBAT), 256, 0, stream>>>(
        W1, x, nullptr, y, nullptr);
    bn_part_kernel<<<dim3(64, NBAT), 256, 0, stream>>>(y, 64, part);
    bn_apply_kernel<<<dim3(2, NBAT * 64), 256, 0, stream>>>(y, g1, b1, part, 64, t);
    lin_mfma_kernel<64, 128, 64, 32, 0, false><<<dim3(64, 2, NBAT), 256, 0, stream>>>(
        W2, t, nullptr, y, nullptr);
    bn_part_kernel<<<dim3(128, NBAT), 256, 0, stream>>>(y, 128, part);
    bn_apply_kernel<<<dim3(2, NBAT * 128), 256, 0, stream>>>(y, g2, b2, part, 128, h);

    for (int blk = 0; blk < 4; ++blk) {
        lin_mfma_kernel<128, 32, 32, 32, 2, false><<<dim3(64, 1, NBAT), 256, 0, stream>>>(
            Wqk + (size_t)blk * 32 * 128, h, nullptr, qThi, qTlo);
        lin_mfma_kernel<128, 128, 64, 32, 1, true><<<dim3(64, 2, NBAT), 256, 0, stream>>>(
            Wv + (size_t)blk * 128 * 128, h, bv + blk * 128, vb, nullptr);
        rowstats_fused_kernel<<<dim3(128, NBAT), 256, 0, stream>>>(qThi, qTlo, rowm, rowinv);
        attn_fused_kernel<<<dim3(64, NBAT), 512, 0, stream>>>(
            qThi, qTlo, vb, rowm, rowinv, h, t);
        lin_mfma_kernel<128, 128, 64, 32, 0, true><<<dim3(64, 2, NBAT), 256, 0, stream>>>(
            Wt + (size_t)blk * 128 * 128, t, bt + blk * 128, y, nullptr);
        bn_part_kernel<<<dim3(128, NBAT), 256, 0, stream>>>(y, 128, part);
        bn_res_kernel<<<dim3(2, NBAT * 128), 256, 0, stream>>>(
            y, gn + blk * 128, bnb + blk * 128, part, h, out, blk);
    }
}